// Round 18
// baseline (429.449 us; speedup 1.0000x reference)
//
#include <hip/hip_runtime.h>
#include <stdint.h>

#define T_TOK 2048
#define HDIM 1024
#define NEXP 8
#define IDIM 3584
#define MAXT1 24
#define MAXT2 40

// ws layout (bytes)
#define WS_CNT   0
#define WS_BASE  64
#define WS_TE1   128
#define WS_TM1   224
#define WS_TE2   320
#define WS_TM2   480
#define WS_NT1   640
#define WS_NT2   644
#define WS_TOK   704
#define WS_GW    (WS_TOK + NEXP * T_TOK * 4)
#define WS_XB    (WS_GW + NEXP * T_TOK * 4)
#define WS_G     (WS_XB + T_TOK * HDIM * 2)
// g: 4096 pairs x IDIM bf16 = 29,360,128 B ; total ~33.7 MB

typedef __attribute__((ext_vector_type(8))) short bf16x8;
typedef __attribute__((ext_vector_type(16))) float f32x16;

__device__ __forceinline__ unsigned short f2bf(float f) {
    union { float f; unsigned int u; } a; a.f = f;
    unsigned int u = a.u;
    return (unsigned short)((u + 0x7fffu + ((u >> 16) & 1u)) >> 16);
}

// packed fp32->bf16 RNE, 2 elems / instr
__device__ __forceinline__ unsigned int cvt_pk_bf16(float lo, float hi) {
    unsigned int r;
    asm("v_cvt_pk_bf16_f32 %0, %1, %2" : "=v"(r) : "v"(lo), "v"(hi));
    return r;
}

__device__ __forceinline__ uint4 pack8(const float4 a, const float4 b) {
    uint4 r;
    r.x = cvt_pk_bf16(a.x, a.y);
    r.y = cvt_pk_bf16(a.z, a.w);
    r.z = cvt_pk_bf16(b.x, b.y);
    r.w = cvt_pk_bf16(b.z, b.w);
    return r;
}

// async global->LDS, 16B per lane; dest = wave-uniform base + lane*16
__device__ __forceinline__ void gload16(const void* gsrc, void* ldst) {
    __builtin_amdgcn_global_load_lds(
        (const __attribute__((address_space(1))) unsigned int*)gsrc,
        (__attribute__((address_space(3))) unsigned int*)ldst, 16, 0, 0);
}

__global__ __launch_bounds__(256) void xcvt_kernel(
    const float* __restrict__ x, unsigned short* __restrict__ xb)
{
    int i = (blockIdx.x * 256 + threadIdx.x) * 8;
    float4 a = *(const float4*)(x + i);
    float4 b = *(const float4*)(x + i + 4);
    *(uint4*)(xb + i) = pack8(a, b);
}

__global__ __launch_bounds__(256) void router_kernel(
    const float* __restrict__ x, const float* __restrict__ gate_w,
    int* __restrict__ cnt, int* __restrict__ tok, float* __restrict__ gw)
{
    int t = blockIdx.x * 4 + (threadIdx.x >> 6);
    int lane = threadIdx.x & 63;
    if (t >= T_TOK) return;
    const float* xr = x + (size_t)t * HDIM;
    float part[NEXP];
#pragma unroll
    for (int e = 0; e < NEXP; e++) part[e] = 0.f;
    for (int h = lane; h < HDIM; h += 64) {
        float xv = xr[h];
#pragma unroll
        for (int e = 0; e < NEXP; e++) part[e] += xv * gate_w[e * HDIM + h];
    }
#pragma unroll
    for (int e = 0; e < NEXP; e++) {
        float v = part[e];
#pragma unroll
        for (int o = 32; o > 0; o >>= 1) v += __shfl_xor(v, o);
        part[e] = v;
    }
    if (lane == 0) {
        int i0 = 0; float v0 = part[0];
#pragma unroll
        for (int e = 1; e < NEXP; e++) if (part[e] > v0) { v0 = part[e]; i0 = e; }
        int i1 = -1; float v1 = -3.4e38f;
#pragma unroll
        for (int e = 0; e < NEXP; e++) if (e != i0 && part[e] > v1) { v1 = part[e]; i1 = e; }
        float d = __expf(v1 - v0);
        float w1v = d / (1.f + d);
        float w0v = 1.f - w1v;
        int p0 = atomicAdd(&cnt[i0], 1);
        tok[i0 * T_TOK + p0] = t; gw[i0 * T_TOK + p0] = w0v;
        int p1 = atomicAdd(&cnt[i1], 1);
        tok[i1 * T_TOK + p1] = t; gw[i1 * T_TOK + p1] = w1v;
    }
}

__global__ void scan_kernel(const int* __restrict__ cnt, int* __restrict__ base,
                            int* __restrict__ tE1, int* __restrict__ tM1,
                            int* __restrict__ nt1p,
                            int* __restrict__ tE2, int* __restrict__ tM2,
                            int* __restrict__ nt2p)
{
    if (threadIdx.x == 0) {
        int s = 0, n1 = 0, n2 = 0;
        for (int e = 0; e < NEXP; e++) {
            base[e] = s; s += cnt[e];
            for (int m0 = 0; m0 < cnt[e]; m0 += 256) { tE1[n1] = e; tM1[n1] = m0; n1++; }
            for (int m0 = 0; m0 < cnt[e]; m0 += 128) { tE2[n2] = e; tM2[n2] = m0; n2++; }
        }
        *nt1p = n1; *nt2p = n2;
    }
}

// ---------------- ffn1: g = silu(x@w1^T) * (x@w3^T) --------------------
// Tile 256 tok x 64 i, BK=32, 4 waves (64-token quarter each, full 64 i).
// Halves weight re-requests vs BM=128 while keeping 3 blocks/CU (LDS 40 KB):
// xs dbuf 2x16K via global_load_lds (R13-proven BK=32 addressing), weights
// reg-staged fp32->bf16 into single-buffered 4K panels.
__global__ __launch_bounds__(256, 3) void ffn1_mfma(
    const unsigned short* __restrict__ xb,
    const float* __restrict__ w1,
    const float* __restrict__ w3,
    const int* __restrict__ cnt, const int* __restrict__ base,
    const int* __restrict__ tok,
    const int* __restrict__ tileE, const int* __restrict__ tileM,
    const int* __restrict__ ntot,
    unsigned short* __restrict__ g)
{
    const int ti = blockIdx.y;
    if (ti >= *ntot) return;
    const int e = tileE[ti];
    const int m0 = tileM[ti];
    const int cntE = cnt[e];
    const int i0 = blockIdx.x * 64;
    const int tid = threadIdx.x;
    const int lane = tid & 63;
    const int wid = tid >> 6;

    __shared__ __align__(16) unsigned char lds[40960];
    // xs[0] @0 (16K = 256 rows x 64B), xs[1] @16384 (16K),
    // w1s @32768 (4K = 64 rows x 64B), w3s @36864 (4K)

    // ---- x gather sources (swizzle pre-folded into per-lane global source)
    const int xrr = (lane >> 2);                 // 0..15 row-in-instr
    const unsigned xoff = ((((unsigned)(lane & 3)) * 16) ^ (((unsigned)(xrr & 3)) << 4)) >> 1;
    const unsigned short* xsrc[4];
#pragma unroll
    for (int i = 0; i < 4; i++) {
        int row = wid * 64 + i * 16 + xrr;
        int t = tok[e * T_TOK + min(m0 + row, cntE - 1)];
        xsrc[i] = xb + (size_t)t * HDIM + xoff;
    }
    const unsigned xdst = (unsigned)(wid * 4096);

    // ---- weight staging (reg -> cvt -> LDS); rows 64B wide (32 bf16)
    const int rw = tid >> 2;                     // 0..63 (i-row)
    const int kq = tid & 3;                      // 8-float chunk
    const unsigned wd = (((unsigned)kq) * 16) ^ (((unsigned)(rw & 3)) << 4);
    const float* w1e = w1 + ((size_t)e * IDIM + i0 + rw) * HDIM + kq * 8;
    const float* w3e = w3 + ((size_t)e * IDIM + i0 + rw) * HDIM + kq * 8;

    f32x16 acc1[2][2], acc3[2][2];               // [m][n]
#pragma unroll
    for (int a = 0; a < 2; a++)
#pragma unroll
        for (int b = 0; b < 2; b++)
#pragma unroll
            for (int r = 0; r < 16; r++) { acc1[a][b][r] = 0.f; acc3[a][b][r] = 0.f; }

    const int fr = lane & 31;
    const int hi = lane >> 5;
    const unsigned lswz = ((unsigned)(fr & 3)) << 4;
    const unsigned hi16 = (unsigned)(hi * 16);
    const unsigned aBase = (unsigned)((wid * 64 + fr) * 64);
    const unsigned bBase = (unsigned)(fr * 64);

    float4 wva[2], wvb[2];

    // prologue: k=0 loads
#pragma unroll
    for (int i = 0; i < 4; i++)
        gload16(xsrc[i], lds + xdst + (unsigned)(i * 1024));
    wva[0] = *(const float4*)(w1e);
    wva[1] = *(const float4*)(w1e + 4);
    wvb[0] = *(const float4*)(w3e);
    wvb[1] = *(const float4*)(w3e + 4);

    const int NST = HDIM / 32;                   // 32 steps
#pragma unroll 1
    for (int st = 0; st < NST; st++) {
        const unsigned xsb = (unsigned)(st & 1) * 16384u;
        const int k0 = st * 32;
        __syncthreads();   // xs[cur] landed (vmcnt drain); prev W reads done
        *(uint4*)(lds + 32768u + rw * 64 + wd) = pack8(wva[0], wva[1]);
        *(uint4*)(lds + 36864u + rw * 64 + wd) = pack8(wvb[0], wvb[1]);
        __syncthreads();   // weight writes visible

        // issue NEXT K-step's loads — fly under the MFMAs + next barrier
        if (k0 + 32 < HDIM) {
            const int kn = k0 + 32;
            const unsigned xnb = xsb ^ 16384u;
#pragma unroll
            for (int i = 0; i < 4; i++)
                gload16(xsrc[i] + kn, lds + xnb + xdst + (unsigned)(i * 1024));
            wva[0] = *(const float4*)(w1e + kn);
            wva[1] = *(const float4*)(w1e + kn + 4);
            wvb[0] = *(const float4*)(w3e + kn);
            wvb[1] = *(const float4*)(w3e + kn + 4);
        }

#pragma unroll
        for (int s = 0; s < 2; s++) {
            const unsigned off = (((unsigned)(s * 32)) + hi16) ^ lswz;
            bf16x8 a0 = *(const bf16x8*)(lds + xsb + aBase + off);
            bf16x8 a1 = *(const bf16x8*)(lds + xsb + aBase + 32 * 64 + off);
            bf16x8 p0 = *(const bf16x8*)(lds + 32768u + bBase + off);
            bf16x8 p1 = *(const bf16x8*)(lds + 32768u + bBase + 32 * 64 + off);
            bf16x8 q0 = *(const bf16x8*)(lds + 36864u + bBase + off);
            bf16x8 q1 = *(const bf16x8*)(lds + 36864u + bBase + 32 * 64 + off);
            acc1[0][0] = __builtin_amdgcn_mfma_f32_32x32x16_bf16(a0, p0, acc1[0][0], 0, 0, 0);
            acc1[0][1] = __builtin_amdgcn_mfma_f32_32x32x16_bf16(a0, p1, acc1[0][1], 0, 0, 0);
            acc1[1][0] = __builtin_amdgcn_mfma_f32_32x32x16_bf16(a1, p0, acc1[1][0], 0, 0, 0);
            acc1[1][1] = __builtin_amdgcn_mfma_f32_32x32x16_bf16(a1, p1, acc1[1][1], 0, 0, 0);
            acc3[0][0] = __builtin_amdgcn_mfma_f32_32x32x16_bf16(a0, q0, acc3[0][0], 0, 0, 0);
            acc3[0][1] = __builtin_amdgcn_mfma_f32_32x32x16_bf16(a0, q1, acc3[0][1], 0, 0, 0);
            acc3[1][0] = __builtin_amdgcn_mfma_f32_32x32x16_bf16(a1, q0, acc3[1][0], 0, 0, 0);
            acc3[1][1] = __builtin_amdgcn_mfma_f32_32x32x16_bf16(a1, q1, acc3[1][1], 0, 0, 0);
        }
    }

    const int pbase = base[e] + m0;
    const int rb4 = 4 * hi;
#pragma unroll
    for (int m = 0; m < 2; m++) {
#pragma unroll
        for (int r = 0; r < 16; r++) {
            int row = (r & 3) + 8 * (r >> 2) + rb4;
            int mm = wid * 64 + m * 32 + row;
            if (m0 + mm < cntE) {
                unsigned short* grow = g + (size_t)(pbase + mm) * IDIM + i0 + fr;
#pragma unroll
                for (int n = 0; n < 2; n++) {
                    float h1 = acc1[m][n][r], h3 = acc3[m][n][r];
                    float v = (h1 / (1.f + __expf(-h1))) * h3;
                    grow[n * 32] = f2bf(v);
                }
            }
        }
    }
}

// ffn2 (R14 config — best ffn2): out[t,h] += gate * (g @ w2^T).
// Tile 128 pairs x 128 h, split-K x4. 2x2 waves, 64x64 per wave. LDS 48 KB.
__global__ __launch_bounds__(256, 3) void ffn2_mfma(
    const unsigned short* __restrict__ g,
    const float* __restrict__ w2,
    const int* __restrict__ cnt, const int* __restrict__ base,
    const int* __restrict__ tok, const float* __restrict__ gw,
    const int* __restrict__ tileE, const int* __restrict__ tileM,
    const int* __restrict__ ntot,
    float* __restrict__ out)
{
    const int ti = blockIdx.y;
    if (ti >= *ntot) return;
    const int e = tileE[ti];
    const int m0 = tileM[ti];
    const int cntE = cnt[e];
    const int pane = blockIdx.x;               // 0..31
    const int h0 = (pane & 7) * 128;
    const int ks = pane >> 3;                  // 0..3
    const int tid = threadIdx.x;
    const int lane = tid & 63;
    const int wid = tid >> 6;

    __shared__ __align__(16) unsigned char lds[49152];
    // GS0 @0 (16K), GS1 @16384 (16K), W2S @32768 (16K)

    const int kbeg = ks * (IDIM / 4);          // 896-elem split, 14 K-steps

    const int xrr = (lane >> 3);
    const unsigned xoff = ((((unsigned)(lane & 7)) * 16) ^ (((unsigned)xrr) << 4)) >> 1;
    const unsigned short* gsrc[4];
    const int be = base[e];
#pragma unroll
    for (int i = 0; i < 4; i++) {
        int row = wid * 32 + i * 8 + xrr;
        int grow = be + min(m0 + row, cntE - 1);
        gsrc[i] = g + (size_t)grow * IDIM + kbeg + xoff;
    }

    const int rw = tid >> 2;                   // 0..63 ; covers h-rows rw, rw+64
    const int kq = tid & 3;
    const unsigned swzW = ((unsigned)(rw & 7)) << 4;
    const unsigned wd0 = (((unsigned)kq) * 32) ^ swzW;
    const unsigned wd1 = (((unsigned)kq) * 32 + 16) ^ swzW;
    const float* w2e = w2 + ((size_t)e * HDIM + h0 + rw) * IDIM + kbeg + kq * 16;
    const size_t rhalf = (size_t)64 * IDIM;

    f32x16 acc[2][2];
#pragma unroll
    for (int a = 0; a < 2; a++)
#pragma unroll
        for (int b = 0; b < 2; b++)
#pragma unroll
            for (int r = 0; r < 16; r++) acc[a][b][r] = 0.f;

    const int wr = wid >> 1;
    const int wc = wid & 1;                    // h half (64 cols)
    const unsigned lrow = (unsigned)(lane & 31);
    const unsigned lswz = (lrow & 7) << 4;
    const unsigned hi16 = (unsigned)((lane >> 5) * 16);
    const unsigned aOff = (wr * 64 + lrow) * 128;
    const unsigned bOff = 32768u + (wc * 64 + lrow) * 128;
    const unsigned xdst = (unsigned)(wid * 32) * 128;

    float4 wv[2][4];

    // prologue
#pragma unroll
    for (int i = 0; i < 4; i++)
        gload16(gsrc[i], lds + xdst + (unsigned)(i * 8) * 128);
#pragma unroll
    for (int h = 0; h < 2; h++)
#pragma unroll
        for (int i = 0; i < 4; i++)
            wv[h][i] = *(const float4*)(w2e + h * rhalf + i * 4);

    const int NST = (IDIM / 4) / 64;           // 14
    for (int st = 0; st < NST; st++) {
        const unsigned xsb = (unsigned)(st & 1) * 16384u;
        const int k0 = st * 64;
        __syncthreads();
#pragma unroll
        for (int h = 0; h < 2; h++) {
            *(uint4*)(lds + 32768u + (rw + h * 64) * 128 + wd0) = pack8(wv[h][0], wv[h][1]);
            *(uint4*)(lds + 32768u + (rw + h * 64) * 128 + wd1) = pack8(wv[h][2], wv[h][3]);
        }
        __syncthreads();

        if (st + 1 < NST) {
            const int kn = k0 + 64;
            const unsigned xnb = xsb ^ 16384u;
#pragma unroll
            for (int i = 0; i < 4; i++)
                gload16(gsrc[i] + kn, lds + xnb + xdst + (unsigned)(i * 8) * 128);
#pragma unroll
            for (int h = 0; h < 2; h++)
#pragma unroll
                for (int i = 0; i < 4; i++)
                    wv[h][i] = *(const float4*)(w2e + h * rhalf + kn + i * 4);
        }

#pragma unroll
        for (int s = 0; s < 4; s++) {
            const unsigned off = (((unsigned)(s * 32)) + hi16) ^ lswz;
            bf16x8 a0 = *(const bf16x8*)(lds + xsb + aOff + off);
            bf16x8 a1 = *(const bf16x8*)(lds + xsb + aOff + 32 * 128 + off);
            bf16x8 b0 = *(const bf16x8*)(lds + bOff + off);
            bf16x8 b1 = *(const bf16x8*)(lds + bOff + 32 * 128 + off);
            acc[0][0] = __builtin_amdgcn_mfma_f32_32x32x16_bf16(a0, b0, acc[0][0], 0, 0, 0);
            acc[0][1] = __builtin_amdgcn_mfma_f32_32x32x16_bf16(a0, b1, acc[0][1], 0, 0, 0);
            acc[1][0] = __builtin_amdgcn_mfma_f32_32x32x16_bf16(a1, b0, acc[1][0], 0, 0, 0);
            acc[1][1] = __builtin_amdgcn_mfma_f32_32x32x16_bf16(a1, b1, acc[1][1], 0, 0, 0);
        }
    }

    const int rb4 = 4 * (lane >> 5);
    const int hcol = h0 + wc * 64 + (int)lrow;
#pragma unroll
    for (int ma = 0; ma < 2; ma++) {
#pragma unroll
        for (int r = 0; r < 16; r++) {
            int row = (r & 3) + 8 * (r >> 2) + rb4;
            int m = wr * 64 + ma * 32 + row;
            if (m0 + m < cntE) {
                int idx = e * T_TOK + m0 + m;
                int t = tok[idx];
                float wgt = gw[idx];
                atomicAdd(out + (size_t)t * HDIM + hcol,      wgt * acc[ma][0][r]);
                atomicAdd(out + (size_t)t * HDIM + hcol + 32, wgt * acc[ma][1][r]);
            }
        }
    }
}

extern "C" void kernel_launch(void* const* d_in, const int* in_sizes, int n_in,
                              void* d_out, int out_size, void* d_ws, size_t ws_size,
                              hipStream_t stream) {
    const float* x      = (const float*)d_in[0];
    const float* gate_w = (const float*)d_in[1];
    const float* w1     = (const float*)d_in[2];
    const float* w2     = (const float*)d_in[3];
    const float* w3     = (const float*)d_in[4];
    float* out = (float*)d_out;
    char* ws = (char*)d_ws;
    int* cnt   = (int*)(ws + WS_CNT);
    int* base  = (int*)(ws + WS_BASE);
    int* tE1   = (int*)(ws + WS_TE1);
    int* tM1   = (int*)(ws + WS_TM1);
    int* tE2   = (int*)(ws + WS_TE2);
    int* tM2   = (int*)(ws + WS_TM2);
    int* nt1   = (int*)(ws + WS_NT1);
    int* nt2   = (int*)(ws + WS_NT2);
    int* tok   = (int*)(ws + WS_TOK);
    float* gw  = (float*)(ws + WS_GW);
    unsigned short* xb = (unsigned short*)(ws + WS_XB);
    unsigned short* g  = (unsigned short*)(ws + WS_G);

    hipMemsetAsync(cnt, 0, 64, stream);
    hipMemsetAsync(d_out, 0, (size_t)out_size * sizeof(float), stream);

    xcvt_kernel<<<T_TOK * HDIM / (256 * 8), 256, 0, stream>>>(x, xb);
    router_kernel<<<T_TOK / 4, 256, 0, stream>>>(x, gate_w, cnt, tok, gw);
    scan_kernel<<<1, 64, 0, stream>>>(cnt, base, tE1, tM1, nt1, tE2, tM2, nt2);
    ffn1_mfma<<<dim3(IDIM / 64, MAXT1), 256, 0, stream>>>(xb, w1, w3, cnt, base, tok, tE1, tM1, nt1, g);
    ffn2_mfma<<<dim3(32, MAXT2), 256, 0, stream>>>(g, w2, cnt, base, tok, gw, tE2, tM2, nt2, out);
}

// Round 19
// 323.671 us; speedup vs baseline: 1.3268x; 1.3268x over previous
//
#include <hip/hip_runtime.h>
#include <stdint.h>

#define T_TOK 2048
#define HDIM 1024
#define NEXP 8
#define IDIM 3584
#define MAXTILE 40

// ws layout (bytes)
#define WS_CNT   0
#define WS_BASE  64
#define WS_TE    128
#define WS_TM    384
#define WS_NT    640
#define WS_TOK   704
#define WS_GW    (WS_TOK + NEXP * T_TOK * 4)
#define WS_XB    (WS_GW + NEXP * T_TOK * 4)
#define WS_G     (WS_XB + T_TOK * HDIM * 2)
// g: 4096 pairs x IDIM bf16 = 29,360,128 B ; total ~33.7 MB

typedef __attribute__((ext_vector_type(8))) short bf16x8;
typedef __attribute__((ext_vector_type(16))) float f32x16;

__device__ __forceinline__ unsigned short f2bf(float f) {
    union { float f; unsigned int u; } a; a.f = f;
    unsigned int u = a.u;
    return (unsigned short)((u + 0x7fffu + ((u >> 16) & 1u)) >> 16);
}

// packed fp32->bf16 RNE, 2 elems / instr
__device__ __forceinline__ unsigned int cvt_pk_bf16(float lo, float hi) {
    unsigned int r;
    asm("v_cvt_pk_bf16_f32 %0, %1, %2" : "=v"(r) : "v"(lo), "v"(hi));
    return r;
}

__device__ __forceinline__ uint4 pack8(const float4 a, const float4 b) {
    uint4 r;
    r.x = cvt_pk_bf16(a.x, a.y);
    r.y = cvt_pk_bf16(a.z, a.w);
    r.z = cvt_pk_bf16(b.x, b.y);
    r.w = cvt_pk_bf16(b.z, b.w);
    return r;
}

// async global->LDS, 16B per lane; dest = wave-uniform base + lane*16
__device__ __forceinline__ void gload16(const void* gsrc, void* ldst) {
    __builtin_amdgcn_global_load_lds(
        (const __attribute__((address_space(1))) unsigned int*)gsrc,
        (__attribute__((address_space(3))) unsigned int*)ldst, 16, 0, 0);
}

__global__ __launch_bounds__(256) void xcvt_kernel(
    const float* __restrict__ x, unsigned short* __restrict__ xb)
{
    int i = (blockIdx.x * 256 + threadIdx.x) * 8;
    float4 a = *(const float4*)(x + i);
    float4 b = *(const float4*)(x + i + 4);
    *(uint4*)(xb + i) = pack8(a, b);
}

__global__ __launch_bounds__(256) void router_kernel(
    const float* __restrict__ x, const float* __restrict__ gate_w,
    int* __restrict__ cnt, int* __restrict__ tok, float* __restrict__ gw)
{
    int t = blockIdx.x * 4 + (threadIdx.x >> 6);
    int lane = threadIdx.x & 63;
    if (t >= T_TOK) return;
    const float* xr = x + (size_t)t * HDIM;
    float part[NEXP];
#pragma unroll
    for (int e = 0; e < NEXP; e++) part[e] = 0.f;
    for (int h = lane; h < HDIM; h += 64) {
        float xv = xr[h];
#pragma unroll
        for (int e = 0; e < NEXP; e++) part[e] += xv * gate_w[e * HDIM + h];
    }
#pragma unroll
    for (int e = 0; e < NEXP; e++) {
        float v = part[e];
#pragma unroll
        for (int o = 32; o > 0; o >>= 1) v += __shfl_xor(v, o);
        part[e] = v;
    }
    if (lane == 0) {
        int i0 = 0; float v0 = part[0];
#pragma unroll
        for (int e = 1; e < NEXP; e++) if (part[e] > v0) { v0 = part[e]; i0 = e; }
        int i1 = -1; float v1 = -3.4e38f;
#pragma unroll
        for (int e = 0; e < NEXP; e++) if (e != i0 && part[e] > v1) { v1 = part[e]; i1 = e; }
        float d = __expf(v1 - v0);
        float w1v = d / (1.f + d);
        float w0v = 1.f - w1v;
        int p0 = atomicAdd(&cnt[i0], 1);
        tok[i0 * T_TOK + p0] = t; gw[i0 * T_TOK + p0] = w0v;
        int p1 = atomicAdd(&cnt[i1], 1);
        tok[i1 * T_TOK + p1] = t; gw[i1 * T_TOK + p1] = w1v;
    }
}

__global__ void scan_kernel(const int* __restrict__ cnt, int* __restrict__ base,
                            int* __restrict__ tileE, int* __restrict__ tileM,
                            int* __restrict__ ntot)
{
    if (threadIdx.x == 0) {
        int s = 0, nt = 0;
        for (int e = 0; e < NEXP; e++) {
            base[e] = s; s += cnt[e];
            for (int m0 = 0; m0 < cnt[e]; m0 += 128) {
                tileE[nt] = e; tileM[nt] = m0; nt++;
            }
        }
        *ntot = nt;
    }
}

// ffn1 (R8 config — best of 10 variants): tile 128 tok x 64 i, BK=64, 4 waves,
// xs double-buffered via global_load_lds (pre-swizzled source), weights
// reg-staged fp32->bf16. LDS 48 KB -> 3 blocks/CU.
__global__ __launch_bounds__(256, 3) void ffn1_mfma(
    const unsigned short* __restrict__ xb,
    const float* __restrict__ w1,
    const float* __restrict__ w3,
    const int* __restrict__ cnt, const int* __restrict__ base,
    const int* __restrict__ tok,
    const int* __restrict__ tileE, const int* __restrict__ tileM,
    const int* __restrict__ ntot,
    unsigned short* __restrict__ g)
{
    const int ti = blockIdx.y;
    if (ti >= *ntot) return;
    const int e = tileE[ti];
    const int m0 = tileM[ti];
    const int cntE = cnt[e];
    const int i0 = blockIdx.x * 64;
    const int tid = threadIdx.x;
    const int lane = tid & 63;
    const int wid = tid >> 6;

    __shared__ __align__(16) unsigned char lds[49152];
    // xs[0] @0 (16K), xs[1] @16384 (16K), w1s @32768 (8K), w3s @40960 (8K)

    // ---- x gather sources for global_load_lds (swizzle folded into source)
    const int xrr = (lane >> 3);                 // 0..7 row-in-instr
    const unsigned xoff = ((((unsigned)(lane & 7)) * 16) ^ (((unsigned)xrr) << 4)) >> 1;
    const unsigned short* xsrc[4];
#pragma unroll
    for (int i = 0; i < 4; i++) {
        int row = wid * 32 + i * 8 + xrr;
        int t = tok[e * T_TOK + min(m0 + row, cntE - 1)];
        xsrc[i] = xb + (size_t)t * HDIM + xoff;
    }

    // ---- weight staging (reg -> cvt -> LDS)
    const int rw = tid >> 2;                     // 0..63 (i-row)
    const int kq = tid & 3;                      // 16-float chunk
    const unsigned swzW = ((unsigned)(rw & 7)) << 4;
    const unsigned wd0 = (((unsigned)kq) * 32) ^ swzW;
    const unsigned wd1 = (((unsigned)kq) * 32 + 16) ^ swzW;
    const float* w1e = w1 + ((size_t)e * IDIM + i0 + rw) * HDIM + kq * 16;
    const float* w3e = w3 + ((size_t)e * IDIM + i0 + rw) * HDIM + kq * 16;

    f32x16 acc1[2], acc3[2];
#pragma unroll
    for (int a = 0; a < 2; a++)
#pragma unroll
        for (int r = 0; r < 16; r++) { acc1[a][r] = 0.f; acc3[a][r] = 0.f; }

    const int wr = wid >> 1;                     // token half (0/1)
    const int wc = wid & 1;                      // i half (0/1) -> 32 cols
    const unsigned lrow = (unsigned)(lane & 31);
    const unsigned lswz = (lrow & 7) << 4;
    const unsigned hi16 = (unsigned)((lane >> 5) * 16);
    const unsigned aRow = (wr * 64 + lrow) * 128;
    const unsigned bRow1 = 32768u + (wc * 32 + lrow) * 128;
    const unsigned bRow3 = 40960u + (wc * 32 + lrow) * 128;

    float4 wva[4], wvb[4];

    // prologue: k=0 loads
#pragma unroll
    for (int i = 0; i < 4; i++)
        gload16(xsrc[i], lds + (wid * 32 + i * 8) * 128);
#pragma unroll
    for (int i = 0; i < 4; i++) {
        wva[i] = *(const float4*)(w1e + i * 4);
        wvb[i] = *(const float4*)(w3e + i * 4);
    }

    for (int st = 0; st < HDIM / 64; st++) {
        const unsigned xsb = (unsigned)(st & 1) * 16384u;
        const int k0 = st * 64;
        __syncthreads();   // xs[cur] landed (vmcnt drain); prev weight reads done
        *(uint4*)(lds + 32768u + rw * 128 + wd0) = pack8(wva[0], wva[1]);
        *(uint4*)(lds + 32768u + rw * 128 + wd1) = pack8(wva[2], wva[3]);
        *(uint4*)(lds + 40960u + rw * 128 + wd0) = pack8(wvb[0], wvb[1]);
        *(uint4*)(lds + 40960u + rw * 128 + wd1) = pack8(wvb[2], wvb[3]);
        __syncthreads();   // weight writes visible

        // issue NEXT K-step's loads — they fly under the MFMAs + next barrier
        if (k0 + 64 < HDIM) {
            const unsigned xnb = xsb ^ 16384u;
#pragma unroll
            for (int i = 0; i < 4; i++)
                gload16(xsrc[i] + k0 + 64, lds + xnb + (wid * 32 + i * 8) * 128);
#pragma unroll
            for (int i = 0; i < 4; i++) {
                wva[i] = *(const float4*)(w1e + k0 + 64 + i * 4);
                wvb[i] = *(const float4*)(w3e + k0 + 64 + i * 4);
            }
        }

#pragma unroll
        for (int s = 0; s < 4; s++) {
            const unsigned off = (((unsigned)(s * 32)) + hi16) ^ lswz;
            bf16x8 a0 = *(const bf16x8*)(lds + xsb + aRow + off);
            bf16x8 a1 = *(const bf16x8*)(lds + xsb + aRow + 32 * 128 + off);
            bf16x8 b1 = *(const bf16x8*)(lds + bRow1 + off);
            bf16x8 b3 = *(const bf16x8*)(lds + bRow3 + off);
            acc1[0] = __builtin_amdgcn_mfma_f32_32x32x16_bf16(a0, b1, acc1[0], 0, 0, 0);
            acc1[1] = __builtin_amdgcn_mfma_f32_32x32x16_bf16(a1, b1, acc1[1], 0, 0, 0);
            acc3[0] = __builtin_amdgcn_mfma_f32_32x32x16_bf16(a0, b3, acc3[0], 0, 0, 0);
            acc3[1] = __builtin_amdgcn_mfma_f32_32x32x16_bf16(a1, b3, acc3[1], 0, 0, 0);
        }
    }

    const int pbase = base[e] + m0;
    const int colI = i0 + wc * 32 + (int)lrow;
    const int rb4 = 4 * (lane >> 5);
#pragma unroll
    for (int ma = 0; ma < 2; ma++) {
#pragma unroll
        for (int r = 0; r < 16; r++) {
            int row = (r & 3) + 8 * (r >> 2) + rb4;
            int m = wr * 64 + ma * 32 + row;
            if (m0 + m < cntE) {
                float h1 = acc1[ma][r], h3 = acc3[ma][r];
                float v = (h1 / (1.f + __expf(-h1))) * h3;
                g[(size_t)(pbase + m) * IDIM + colI] = f2bf(v);
            }
        }
    }
}

// ffn2 (R14 config — best ffn2): out[t,h] += gate * (g @ w2^T).
// Tile 128 pairs x 128 h, split-K x4. 2x2 waves, 64x64 per wave:
// g-panel re-reads halved vs BN=64. LDS 48 KB -> 3 blocks/CU.
__global__ __launch_bounds__(256, 3) void ffn2_mfma(
    const unsigned short* __restrict__ g,
    const float* __restrict__ w2,
    const int* __restrict__ cnt, const int* __restrict__ base,
    const int* __restrict__ tok, const float* __restrict__ gw,
    const int* __restrict__ tileE, const int* __restrict__ tileM,
    const int* __restrict__ ntot,
    float* __restrict__ out)
{
    const int ti = blockIdx.y;
    if (ti >= *ntot) return;
    const int e = tileE[ti];
    const int m0 = tileM[ti];
    const int cntE = cnt[e];
    const int pane = blockIdx.x;               // 0..31
    const int h0 = (pane & 7) * 128;
    const int ks = pane >> 3;                  // 0..3
    const int tid = threadIdx.x;
    const int lane = tid & 63;
    const int wid = tid >> 6;

    __shared__ __align__(16) unsigned char lds[49152];
    // GS0 @0 (16K), GS1 @16384 (16K), W2S @32768 (16K)

    const int kbeg = ks * (IDIM / 4);          // 896-elem split, 14 K-steps

    const int xrr = (lane >> 3);
    const unsigned xoff = ((((unsigned)(lane & 7)) * 16) ^ (((unsigned)xrr) << 4)) >> 1;
    const unsigned short* gsrc[4];
    const int be = base[e];
#pragma unroll
    for (int i = 0; i < 4; i++) {
        int row = wid * 32 + i * 8 + xrr;
        int grow = be + min(m0 + row, cntE - 1);
        gsrc[i] = g + (size_t)grow * IDIM + kbeg + xoff;
    }

    const int rw = tid >> 2;                   // 0..63 ; covers h-rows rw, rw+64
    const int kq = tid & 3;
    const unsigned swzW = ((unsigned)(rw & 7)) << 4;
    const unsigned wd0 = (((unsigned)kq) * 32) ^ swzW;
    const unsigned wd1 = (((unsigned)kq) * 32 + 16) ^ swzW;
    const float* w2e = w2 + ((size_t)e * HDIM + h0 + rw) * IDIM + kbeg + kq * 16;
    const size_t rhalf = (size_t)64 * IDIM;

    f32x16 acc[2][2];
#pragma unroll
    for (int a = 0; a < 2; a++)
#pragma unroll
        for (int b = 0; b < 2; b++)
#pragma unroll
            for (int r = 0; r < 16; r++) acc[a][b][r] = 0.f;

    const int wr = wid >> 1;
    const int wc = wid & 1;                    // h half (64 cols)
    const unsigned lrow = (unsigned)(lane & 31);
    const unsigned lswz = (lrow & 7) << 4;
    const unsigned hi16 = (unsigned)((lane >> 5) * 16);
    const unsigned aOff = (wr * 64 + lrow) * 128;
    const unsigned bOff = 32768u + (wc * 64 + lrow) * 128;
    const unsigned xdst = (unsigned)(wid * 32) * 128;

    float4 wv[2][4];

    // prologue
#pragma unroll
    for (int i = 0; i < 4; i++)
        gload16(gsrc[i], lds + xdst + (unsigned)(i * 8) * 128);
#pragma unroll
    for (int h = 0; h < 2; h++)
#pragma unroll
        for (int i = 0; i < 4; i++)
            wv[h][i] = *(const float4*)(w2e + h * rhalf + i * 4);

    const int NST = (IDIM / 4) / 64;           // 14
    for (int st = 0; st < NST; st++) {
        const unsigned xsb = (unsigned)(st & 1) * 16384u;
        const int k0 = st * 64;
        __syncthreads();
#pragma unroll
        for (int h = 0; h < 2; h++) {
            *(uint4*)(lds + 32768u + (rw + h * 64) * 128 + wd0) = pack8(wv[h][0], wv[h][1]);
            *(uint4*)(lds + 32768u + (rw + h * 64) * 128 + wd1) = pack8(wv[h][2], wv[h][3]);
        }
        __syncthreads();

        if (st + 1 < NST) {
            const int kn = k0 + 64;
            const unsigned xnb = xsb ^ 16384u;
#pragma unroll
            for (int i = 0; i < 4; i++)
                gload16(gsrc[i] + kn, lds + xnb + xdst + (unsigned)(i * 8) * 128);
#pragma unroll
            for (int h = 0; h < 2; h++)
#pragma unroll
                for (int i = 0; i < 4; i++)
                    wv[h][i] = *(const float4*)(w2e + h * rhalf + kn + i * 4);
        }

#pragma unroll
        for (int s = 0; s < 4; s++) {
            const unsigned off = (((unsigned)(s * 32)) + hi16) ^ lswz;
            bf16x8 a0 = *(const bf16x8*)(lds + xsb + aOff + off);
            bf16x8 a1 = *(const bf16x8*)(lds + xsb + aOff + 32 * 128 + off);
            bf16x8 b0 = *(const bf16x8*)(lds + bOff + off);
            bf16x8 b1 = *(const bf16x8*)(lds + bOff + 32 * 128 + off);
            acc[0][0] = __builtin_amdgcn_mfma_f32_32x32x16_bf16(a0, b0, acc[0][0], 0, 0, 0);
            acc[0][1] = __builtin_amdgcn_mfma_f32_32x32x16_bf16(a0, b1, acc[0][1], 0, 0, 0);
            acc[1][0] = __builtin_amdgcn_mfma_f32_32x32x16_bf16(a1, b0, acc[1][0], 0, 0, 0);
            acc[1][1] = __builtin_amdgcn_mfma_f32_32x32x16_bf16(a1, b1, acc[1][1], 0, 0, 0);
        }
    }

    const int rb4 = 4 * (lane >> 5);
    const int hcol = h0 + wc * 64 + (int)lrow;
#pragma unroll
    for (int ma = 0; ma < 2; ma++) {
#pragma unroll
        for (int r = 0; r < 16; r++) {
            int row = (r & 3) + 8 * (r >> 2) + rb4;
            int m = wr * 64 + ma * 32 + row;
            if (m0 + m < cntE) {
                int idx = e * T_TOK + m0 + m;
                int t = tok[idx];
                float wgt = gw[idx];
                atomicAdd(out + (size_t)t * HDIM + hcol,      wgt * acc[ma][0][r]);
                atomicAdd(out + (size_t)t * HDIM + hcol + 32, wgt * acc[ma][1][r]);
            }
        }
    }
}

extern "C" void kernel_launch(void* const* d_in, const int* in_sizes, int n_in,
                              void* d_out, int out_size, void* d_ws, size_t ws_size,
                              hipStream_t stream) {
    const float* x      = (const float*)d_in[0];
    const float* gate_w = (const float*)d_in[1];
    const float* w1     = (const float*)d_in[2];
    const float* w2     = (const float*)d_in[3];
    const float* w3     = (const float*)d_in[4];
    float* out = (float*)d_out;
    char* ws = (char*)d_ws;
    int* cnt   = (int*)(ws + WS_CNT);
    int* base  = (int*)(ws + WS_BASE);
    int* tileE = (int*)(ws + WS_TE);
    int* tileM = (int*)(ws + WS_TM);
    int* ntot  = (int*)(ws + WS_NT);
    int* tok   = (int*)(ws + WS_TOK);
    float* gw  = (float*)(ws + WS_GW);
    unsigned short* xb = (unsigned short*)(ws + WS_XB);
    unsigned short* g  = (unsigned short*)(ws + WS_G);

    hipMemsetAsync(cnt, 0, 64, stream);
    hipMemsetAsync(d_out, 0, (size_t)out_size * sizeof(float), stream);

    xcvt_kernel<<<T_TOK * HDIM / (256 * 8), 256, 0, stream>>>(x, xb);
    router_kernel<<<T_TOK / 4, 256, 0, stream>>>(x, gate_w, cnt, tok, gw);
    scan_kernel<<<1, 64, 0, stream>>>(cnt, base, tileE, tileM, ntot);
    ffn1_mfma<<<dim3(IDIM / 64, MAXTILE), 256, 0, stream>>>(xb, w1, w3, cnt, base, tok, tileE, tileM, ntot, g);
    ffn2_mfma<<<dim3(32, MAXTILE), 256, 0, stream>>>(g, w2, cnt, base, tok, gw, tileE, tileM, ntot, out);
}